// Round 4
// baseline (460.800 us; speedup 1.0000x reference)
//
#include <hip/hip_runtime.h>
#include <float.h>
#include <math.h>

// Problem constants (reference: x shape (2,1024,32000) fp32, dim=-1, alpha=1.5)
#define D_DIM   32000
#define NT      256                         // 4 waves -> 8 blocks/CU
#define CHUNKS  (D_DIM / 4)                 // 8000 float4 chunks per row
#define KITER   ((CHUNKS + NT - 1) / NT)    // 32 strided iterations per thread
#define NWAVES  (NT / 64)                   // 4
#define CAPL    18                          // candidate slots per lane
#define SEG     (64 * CAPL)                 // floats per wave segment (1152)

typedef float f32x4 __attribute__((ext_vector_type(4)));

__device__ __forceinline__ float waveReduceSum(float v) {
#pragma unroll
    for (int m = 32; m >= 1; m >>= 1) v += __shfl_xor(v, m, 64);
    return v;
}

__device__ __forceinline__ float waveReduceMax(float v) {
#pragma unroll
    for (int m = 32; m >= 1; m >>= 1) v = fmaxf(v, __shfl_xor(v, m, 64));
    return v;
}

// Bit-level finite scrub: maps NaN and +/-inf to -FLT_MAX. Integer-domain so
// -ffinite-math-only cannot fold it away.
__device__ __forceinline__ float scrub_finite(float v) {
    const unsigned u = __float_as_uint(v);
    if ((u & 0x7f800000u) == 0x7f800000u) return -FLT_MAX;
    return v;
}

// Lane-local eviction: drop column entries <= thr. Entries <= runM-1 with
// runM <= final max contribute exactly 0 to every f(tau) evaluated at
// tau >= max-1, so eviction never changes any later sum.
__device__ __forceinline__ int compact_col(float* __restrict__ seg, int lane, float thr) {
    int m = 0;
#pragma unroll
    for (int i = 0; i < CAPL; ++i) {
        const float v = seg[i * 64 + lane];
        if (v > thr) { seg[m * 64 + lane] = v; ++m; }   // m <= i: in-place safe
    }
#pragma unroll
    for (int i = 0; i < CAPL; ++i)
        if (i >= m) seg[i * 64 + lane] = -FLT_MAX;      // clear stale tail
    return m;
}

// ---------------- K1: tau solver ----------------
// Streams the row once (running-max admission + lane-local eviction into LDS),
// 4-wave bisection on the compacted set, stashes (tau_m, s_final) in the first
// 8 bytes of the OUTPUT row. K2 reads the stash then overwrites everything.
// No reread, no epilogue: this kernel's HBM cost is one clean input stream.
__global__ __launch_bounds__(NT, 8)
void entmax_tau_kernel(const float* __restrict__ x, float* __restrict__ out, int rows)
{
    const int row = blockIdx.x;
    if (row >= rows) return;
    const size_t base = (size_t)row * D_DIM;
    const float4* __restrict__ xr4 = reinterpret_cast<const float4*>(x + base);

    __shared__ __align__(16) float s_act[NWAVES * SEG];   // 18 KB
    __shared__ float s_red[NWAVES];
    __shared__ int   s_flag;

    const int lane = threadIdx.x & 63;
    const int wv   = threadIdx.x >> 6;
    float* __restrict__ seg = s_act + wv * SEG;

    // ---- init pads ----
    {
        f32x4* sa4 = reinterpret_cast<f32x4*>(s_act);
#pragma unroll 2
        for (int i = threadIdx.x; i < (NWAVES * SEG) / 4; i += NT)
            sa4[i] = (f32x4){-FLT_MAX, -FLT_MAX, -FLT_MAX, -FLT_MAX};
        if (threadIdx.x == 0) s_flag = 0;
    }
    __syncthreads();

    // ---- pass 1: stream row; wave running max + single-pass candidate compaction ----
    float runM = -FLT_MAX;
    int n = 0;
    int ovf = 0;
    for (int k = 0; k < KITER; ++k) {
        const int c = threadIdx.x + k * NT;
        float z0, z1, z2, z3;
        if (c < CHUNKS) {
            const float4 v = xr4[c];
            z0 = v.x * 0.5f; z1 = v.y * 0.5f; z2 = v.z * 0.5f; z3 = v.w * 0.5f;
        } else {
            z0 = z1 = z2 = z3 = -FLT_MAX;
        }
        float cm = fmaxf(fmaxf(z0, z1), fmaxf(z2, z3));
        cm = waveReduceMax(cm);
        runM = fmaxf(runM, cm);
        const float thr = runM - 1.0f;
        const int adm = (z0 > thr) + (z1 > thr) + (z2 > thr) + (z3 > thr);
        if (adm) {
            if (n + adm > CAPL) n = compact_col(seg, lane, thr);
            if (n + adm > CAPL) {
                ovf = 1;
            } else {
                if (z0 > thr) { seg[n * 64 + lane] = z0; ++n; }
                if (z1 > thr) { seg[n * 64 + lane] = z1; ++n; }
                if (z2 > thr) { seg[n * 64 + lane] = z2; ++n; }
                if (z3 > thr) { seg[n * 64 + lane] = z3; ++n; }
            }
        }
    }
    if (ovf) s_flag = 1;   // benign race

    if (lane == 0) s_red[wv] = runM;
    __syncthreads();
    const float max_val = fmaxf(fmaxf(s_red[0], s_red[1]), fmaxf(s_red[2], s_red[3]));
    const int flag = s_flag;
    __syncthreads();                     // s_red is reused below

    float tau_lo = max_val - 1.0f;                          // gp(1) = 1
    const float tau_hi = max_val - 0.005590169943749474f;   // (1/32000)^0.5
    float tau_m, s_final;

    if (!flag) {
        // ---- 4-wave bisection: each wave scans its own padded segment ----
        float fl = 0.0f;
#pragma unroll
        for (int k = 0; k < CAPL; ++k) {
            const float t = fmaxf(seg[k * 64 + lane] - tau_lo, 0.0f);
            fl = fmaf(t, t, fl);
        }
        fl = waveReduceSum(fl);
        if (lane == 0) s_red[wv] = fl;
        __syncthreads();
        const float f_lo = (s_red[0] + s_red[1] + s_red[2] + s_red[3]) - 1.0f;
        __syncthreads();

        float dm = tau_hi - tau_lo;
        tau_m = tau_lo;
        s_final = 1.0f;
        for (int it = 0; it < 100; ++it) {
            dm *= 0.5f;
            tau_m = tau_lo + dm;
            const bool fixed = (tau_m == tau_lo);   // uniform across block
            float a = 0.0f;
#pragma unroll
            for (int k = 0; k < CAPL; ++k) {
                const float t = fmaxf(seg[k * 64 + lane] - tau_m, 0.0f);
                a = fmaf(t, t, a);
            }
            a = waveReduceSum(a);
            if (lane == 0) s_red[wv] = a;
            __syncthreads();
            const float s = s_red[0] + s_red[1] + s_red[2] + s_red[3];
            __syncthreads();
            s_final = s;
            if ((s - 1.0f) * f_lo >= 0.0f) tau_lo = tau_m;
            if (fixed) break;
        }
    } else {
        // ---- fallback (rare: low-max rows): stream row per iteration ----
        float acc = 0.0f;
        for (int k = 0; k < KITER; ++k) {
            const int c = threadIdx.x + k * NT;
            if (c < CHUNKS) {
                const float4 v = xr4[c];
                float t;
                t = fmaxf(v.x * 0.5f - tau_lo, 0.0f); acc = fmaf(t, t, acc);
                t = fmaxf(v.y * 0.5f - tau_lo, 0.0f); acc = fmaf(t, t, acc);
                t = fmaxf(v.z * 0.5f - tau_lo, 0.0f); acc = fmaf(t, t, acc);
                t = fmaxf(v.w * 0.5f - tau_lo, 0.0f); acc = fmaf(t, t, acc);
            }
        }
        acc = waveReduceSum(acc);
        if (lane == 0) s_red[wv] = acc;
        __syncthreads();
        const float f_lo = (s_red[0] + s_red[1] + s_red[2] + s_red[3]) - 1.0f;
        __syncthreads();

        float dm = tau_hi - tau_lo;
        tau_m = tau_lo;
        s_final = 1.0f;
        for (int it = 0; it < 100; ++it) {
            dm *= 0.5f;
            tau_m = tau_lo + dm;
            const bool fixed = (tau_m == tau_lo);
            float a = 0.0f;
            for (int k = 0; k < KITER; ++k) {
                const int c = threadIdx.x + k * NT;
                if (c < CHUNKS) {
                    const float4 v = xr4[c];
                    float t;
                    t = fmaxf(v.x * 0.5f - tau_m, 0.0f); a = fmaf(t, t, a);
                    t = fmaxf(v.y * 0.5f - tau_m, 0.0f); a = fmaf(t, t, a);
                    t = fmaxf(v.z * 0.5f - tau_m, 0.0f); a = fmaf(t, t, a);
                    t = fmaxf(v.w * 0.5f - tau_m, 0.0f); a = fmaf(t, t, a);
                }
            }
            a = waveReduceSum(a);
            if (lane == 0) s_red[wv] = a;
            __syncthreads();
            const float s = s_red[0] + s_red[1] + s_red[2] + s_red[3];
            __syncthreads();
            s_final = s;
            if ((s - 1.0f) * f_lo >= 0.0f) tau_lo = tau_m;
            if (fixed) break;
        }
    }

    // ---- stash (tau_m, s_final) in the first 8 bytes of the output row ----
    if (threadIdx.x == 0) {
        float2 ts; ts.x = tau_m; ts.y = s_final;
        *reinterpret_cast<float2*>(out + base) = ts;
    }
}

// ---------------- K2: elementwise epilogue ----------------
// Reads the stash, then streams x -> log(p/sum) with the verified numeric
// path (floor p before log, bit-scrub residual inf/NaN), nt-stores out.
__global__ __launch_bounds__(NT, 8)
void entmax_finish_kernel(const float* __restrict__ x, float* __restrict__ out, int rows)
{
    const int row = blockIdx.x;
    if (row >= rows) return;
    const size_t base = (size_t)row * D_DIM;
    const float4* __restrict__ xr4 = reinterpret_cast<const float4*>(x + base);
    float* __restrict__ orow = out + base;

    __shared__ float2 s_ts;
    if (threadIdx.x == 0) s_ts = *reinterpret_cast<const float2*>(orow);
    __syncthreads();   // all threads see the stash before anyone overwrites it
    const float tau_m = s_ts.x;
    const float inv_s = 1.0f / s_ts.y;

    for (int k = 0; k < KITER; ++k) {
        const int c = threadIdx.x + k * NT;
        if (c < CHUNKS) {
            const float4 v = xr4[c];
            f32x4 o;
            {
                const float t = fmaxf(v.x * 0.5f - tau_m, 0.0f);
                o.x = scrub_finite(__logf(fmaxf(t * t, 1e-35f) * inv_s));
            }
            {
                const float t = fmaxf(v.y * 0.5f - tau_m, 0.0f);
                o.y = scrub_finite(__logf(fmaxf(t * t, 1e-35f) * inv_s));
            }
            {
                const float t = fmaxf(v.z * 0.5f - tau_m, 0.0f);
                o.z = scrub_finite(__logf(fmaxf(t * t, 1e-35f) * inv_s));
            }
            {
                const float t = fmaxf(v.w * 0.5f - tau_m, 0.0f);
                o.w = scrub_finite(__logf(fmaxf(t * t, 1e-35f) * inv_s));
            }
            __builtin_nontemporal_store(o, reinterpret_cast<f32x4*>(orow) + c);
        }
    }
}

extern "C" void kernel_launch(void* const* d_in, const int* in_sizes, int n_in,
                              void* d_out, int out_size, void* d_ws, size_t ws_size,
                              hipStream_t stream) {
    const float* x = (const float*)d_in[0];
    float* out = (float*)d_out;
    const int rows = in_sizes[0] / D_DIM;
    entmax_tau_kernel<<<dim3(rows), dim3(NT), 0, stream>>>(x, out, rows);
    entmax_finish_kernel<<<dim3(rows), dim3(NT), 0, stream>>>(x, out, rows);
}

// Round 5
// 166.684 us; speedup vs baseline: 2.7645x; 2.7645x over previous
//
#include <hip/hip_runtime.h>
#include <float.h>
#include <math.h>

// Problem constants (reference: x shape (2,1024,32000) fp32, dim=-1, alpha=1.5)
#define D_DIM   32000
#define NT      256                         // 4 waves -> 8 blocks/CU
#define CHUNKS  (D_DIM / 4)                 // 8000 float4 chunks per row
#define KITER   ((CHUNKS + NT - 1) / NT)    // 32 strided iterations per thread
#define NGROUP  (KITER / 2)                 // 16 two-chunk groups
#define NWAVES  (NT / 64)                   // 4
#define CAPW    1248                        // per-wave pool capacity (4992 B)

typedef float f32x4 __attribute__((ext_vector_type(4)));
typedef unsigned long long ull;

__device__ __forceinline__ float waveReduceSum(float v) {
#pragma unroll
    for (int m = 32; m >= 1; m >>= 1) v += __shfl_xor(v, m, 64);
    return v;
}

__device__ __forceinline__ float waveReduceMax(float v) {
#pragma unroll
    for (int m = 32; m >= 1; m >>= 1) v = fmaxf(v, __shfl_xor(v, m, 64));
    return v;
}

// Bit-level finite scrub: maps NaN and +/-inf to -FLT_MAX. Integer-domain so
// -ffinite-math-only cannot fold it away.
__device__ __forceinline__ float scrub_finite(float v) {
    const unsigned u = __float_as_uint(v);
    if ((u & 0x7f800000u) == 0x7f800000u) return -FLT_MAX;
    return v;
}

// ---------------- K1: tau solver ----------------
// Streams the row once. Candidates {z > runM-1} go into a PER-WAVE shared
// pool via ballot+prefix-rank append (deterministic order). R4 lesson: the
// per-LANE column capacity (18) was exceeded by low-max waves, where the
// live count per lane is Binom(128, Phic(M-2)) with p up to ~0.15 -> the
// fallback streamed HBM on a large row fraction (FETCH 4.5x input, 430us).
// A wave-shared pool absorbs the per-lane variance: wave live <= 8192*p
// needs p <= 0.152 (CAPW=1248), violated only at P~3e-6 per wave.
// When full, wave-cooperatively evict entries <= runM-1 (they contribute
// exactly 0 to every f(tau) at tau >= max-1: stable, deterministic).
__global__ __launch_bounds__(NT, 8)
void entmax_tau_kernel(const float* __restrict__ x, float* __restrict__ out, int rows)
{
    const int row = blockIdx.x;
    if (row >= rows) return;
    const size_t base = (size_t)row * D_DIM;
    const float4* __restrict__ xr4 = reinterpret_cast<const float4*>(x + base);

    __shared__ __align__(16) float s_pool[NWAVES * CAPW];   // 19968 B
    __shared__ float s_red[NWAVES];
    __shared__ int   s_flag;

    const int lane = threadIdx.x & 63;
    const int wv   = threadIdx.x >> 6;
    float* __restrict__ wpool = s_pool + wv * CAPW;
    const ull lmask = (1ull << lane) - 1ull;

    if (threadIdx.x == 0) s_flag = 0;
    __syncthreads();

    // ---- pass 1: stream row; per-2-chunk wave max update + pooled admission ----
    float runM = -FLT_MAX;
    int n = 0;           // wave-uniform pool count
    bool ovf = false;    // wave-uniform
    for (int g = 0; g < NGROUP; ++g) {
        const int c0 = threadIdx.x + (2 * g) * NT;
        const int c1 = threadIdx.x + (2 * g + 1) * NT;
        float z[8];
        if (c0 < CHUNKS) {
            const float4 v = xr4[c0];
            z[0] = v.x * 0.5f; z[1] = v.y * 0.5f; z[2] = v.z * 0.5f; z[3] = v.w * 0.5f;
        } else { z[0] = z[1] = z[2] = z[3] = -FLT_MAX; }
        if (c1 < CHUNKS) {
            const float4 v = xr4[c1];
            z[4] = v.x * 0.5f; z[5] = v.y * 0.5f; z[6] = v.z * 0.5f; z[7] = v.w * 0.5f;
        } else { z[4] = z[5] = z[6] = z[7] = -FLT_MAX; }

        float cm = fmaxf(fmaxf(fmaxf(z[0], z[1]), fmaxf(z[2], z[3])),
                         fmaxf(fmaxf(z[4], z[5]), fmaxf(z[6], z[7])));
        cm = waveReduceMax(cm);
        runM = fmaxf(runM, cm);
        const float thr = runM - 1.0f;

        ull msk[8];
        int tot = 0;
#pragma unroll
        for (int j = 0; j < 8; ++j) {
            msk[j] = __ballot(z[j] > thr);
            tot += __popcll(msk[j]);
        }
        if (tot) {
            if (n + tot > CAPW) {
                // wave-cooperative stable compaction: keep entries > thr.
                // dest index (nn+rank) <= segment base; same-wave DS ops are
                // program-ordered, and all lanes read before any lane writes.
                int nn = 0;
                for (int i = 0; i < n; i += 64) {
                    const float v = (i + lane < n) ? wpool[i + lane] : -FLT_MAX;
                    const ull km = __ballot(v > thr);
                    const int r = __popcll(km & lmask);
                    if (v > thr) wpool[nn + r] = v;
                    nn += __popcll(km);
                }
                n = nn;
            }
            if (n + tot > CAPW) {
                ovf = true;          // adversarial/degenerate rows only
            } else {
#pragma unroll
                for (int j = 0; j < 8; ++j) {
                    if (z[j] > thr) {
                        const int r = __popcll(msk[j] & lmask);
                        wpool[n + r] = z[j];
                    }
                    n += __popcll(msk[j]);
                }
            }
        }
    }
    if (ovf && lane == 0) s_flag = 1;   // benign race across waves

    if (lane == 0) s_red[wv] = runM;
    __syncthreads();
    const float max_val = fmaxf(fmaxf(s_red[0], s_red[1]), fmaxf(s_red[2], s_red[3]));
    const int flag = s_flag;
    __syncthreads();                     // s_red is reused below

    float tau_lo = max_val - 1.0f;                          // gp(1) = 1
    const float tau_hi = max_val - 0.005590169943749474f;   // (1/32000)^0.5
    float tau_m, s_final;

    if (!flag) {
        // ---- 4-wave bisection: each wave scans its own pool [0, n) ----
        float fl = 0.0f;
        for (int i = lane; i < n; i += 64) {
            const float t = fmaxf(wpool[i] - tau_lo, 0.0f);
            fl = fmaf(t, t, fl);
        }
        fl = waveReduceSum(fl);
        if (lane == 0) s_red[wv] = fl;
        __syncthreads();
        const float f_lo = (s_red[0] + s_red[1] + s_red[2] + s_red[3]) - 1.0f;
        __syncthreads();

        float dm = tau_hi - tau_lo;
        tau_m = tau_lo;
        s_final = 1.0f;
        for (int it = 0; it < 100; ++it) {
            dm *= 0.5f;
            tau_m = tau_lo + dm;
            const bool fixed = (tau_m == tau_lo);   // uniform across block
            float a = 0.0f;
            for (int i = lane; i < n; i += 64) {
                const float t = fmaxf(wpool[i] - tau_m, 0.0f);
                a = fmaf(t, t, a);
            }
            a = waveReduceSum(a);
            if (lane == 0) s_red[wv] = a;
            __syncthreads();
            const float s = s_red[0] + s_red[1] + s_red[2] + s_red[3];
            __syncthreads();
            s_final = s;
            if ((s - 1.0f) * f_lo >= 0.0f) tau_lo = tau_m;
            if (fixed) break;
        }
    } else {
        // ---- fallback (degenerate rows only): stream row per iteration ----
        float acc = 0.0f;
        for (int k = 0; k < KITER; ++k) {
            const int c = threadIdx.x + k * NT;
            if (c < CHUNKS) {
                const float4 v = xr4[c];
                float t;
                t = fmaxf(v.x * 0.5f - tau_lo, 0.0f); acc = fmaf(t, t, acc);
                t = fmaxf(v.y * 0.5f - tau_lo, 0.0f); acc = fmaf(t, t, acc);
                t = fmaxf(v.z * 0.5f - tau_lo, 0.0f); acc = fmaf(t, t, acc);
                t = fmaxf(v.w * 0.5f - tau_lo, 0.0f); acc = fmaf(t, t, acc);
            }
        }
        acc = waveReduceSum(acc);
        if (lane == 0) s_red[wv] = acc;
        __syncthreads();
        const float f_lo = (s_red[0] + s_red[1] + s_red[2] + s_red[3]) - 1.0f;
        __syncthreads();

        float dm = tau_hi - tau_lo;
        tau_m = tau_lo;
        s_final = 1.0f;
        for (int it = 0; it < 100; ++it) {
            dm *= 0.5f;
            tau_m = tau_lo + dm;
            const bool fixed = (tau_m == tau_lo);
            float a = 0.0f;
            for (int k = 0; k < KITER; ++k) {
                const int c = threadIdx.x + k * NT;
                if (c < CHUNKS) {
                    const float4 v = xr4[c];
                    float t;
                    t = fmaxf(v.x * 0.5f - tau_m, 0.0f); a = fmaf(t, t, a);
                    t = fmaxf(v.y * 0.5f - tau_m, 0.0f); a = fmaf(t, t, a);
                    t = fmaxf(v.z * 0.5f - tau_m, 0.0f); a = fmaf(t, t, a);
                    t = fmaxf(v.w * 0.5f - tau_m, 0.0f); a = fmaf(t, t, a);
                }
            }
            a = waveReduceSum(a);
            if (lane == 0) s_red[wv] = a;
            __syncthreads();
            const float s = s_red[0] + s_red[1] + s_red[2] + s_red[3];
            __syncthreads();
            s_final = s;
            if ((s - 1.0f) * f_lo >= 0.0f) tau_lo = tau_m;
            if (fixed) break;
        }
    }

    // ---- stash (tau_m, s_final) in the first 8 bytes of the output row ----
    if (threadIdx.x == 0) {
        float2 ts; ts.x = tau_m; ts.y = s_final;
        *reinterpret_cast<float2*>(out + base) = ts;
    }
}

// ---------------- K2: elementwise epilogue ----------------
// Reads the stash, then streams x -> log(p/sum) with the verified numeric
// path (floor p before log, bit-scrub residual inf/NaN), nt-stores out.
__global__ __launch_bounds__(NT, 8)
void entmax_finish_kernel(const float* __restrict__ x, float* __restrict__ out, int rows)
{
    const int row = blockIdx.x;
    if (row >= rows) return;
    const size_t base = (size_t)row * D_DIM;
    const float4* __restrict__ xr4 = reinterpret_cast<const float4*>(x + base);
    float* __restrict__ orow = out + base;

    __shared__ float2 s_ts;
    if (threadIdx.x == 0) s_ts = *reinterpret_cast<const float2*>(orow);
    __syncthreads();   // all threads see the stash before anyone overwrites it
    const float tau_m = s_ts.x;
    const float inv_s = 1.0f / s_ts.y;

    for (int k = 0; k < KITER; ++k) {
        const int c = threadIdx.x + k * NT;
        if (c < CHUNKS) {
            const float4 v = xr4[c];
            f32x4 o;
            {
                const float t = fmaxf(v.x * 0.5f - tau_m, 0.0f);
                o.x = scrub_finite(__logf(fmaxf(t * t, 1e-35f) * inv_s));
            }
            {
                const float t = fmaxf(v.y * 0.5f - tau_m, 0.0f);
                o.y = scrub_finite(__logf(fmaxf(t * t, 1e-35f) * inv_s));
            }
            {
                const float t = fmaxf(v.z * 0.5f - tau_m, 0.0f);
                o.z = scrub_finite(__logf(fmaxf(t * t, 1e-35f) * inv_s));
            }
            {
                const float t = fmaxf(v.w * 0.5f - tau_m, 0.0f);
                o.w = scrub_finite(__logf(fmaxf(t * t, 1e-35f) * inv_s));
            }
            __builtin_nontemporal_store(o, reinterpret_cast<f32x4*>(orow) + c);
        }
    }
}

extern "C" void kernel_launch(void* const* d_in, const int* in_sizes, int n_in,
                              void* d_out, int out_size, void* d_ws, size_t ws_size,
                              hipStream_t stream) {
    const float* x = (const float*)d_in[0];
    float* out = (float*)d_out;
    const int rows = in_sizes[0] / D_DIM;
    entmax_tau_kernel<<<dim3(rows), dim3(NT), 0, stream>>>(x, out, rows);
    entmax_finish_kernel<<<dim3(rows), dim3(NT), 0, stream>>>(x, out, rows);
}